// Round 12
// baseline (247.866 us; speedup 1.0000x reference)
//
#include <hip/hip_runtime.h>

// Problem constants (fixed by setup_inputs)
#define B_  2
#define CK_ 64
#define CV_ 512
#define H_  48
#define W_  48
#define M_  18432   // T*H*W
#define N_  2304    // H*W

#define SSPLIT 8
#define MSEG   (M_ / SSPLIT)   // 2304
#define VSTRIDE16 (CV_ * 16)   // elems per m16 block in vt = 8192

typedef __bf16 bf16x8 __attribute__((ext_vector_type(8)));
typedef float  f32x4  __attribute__((ext_vector_type(4)));
typedef float  f32x16 __attribute__((ext_vector_type(16)));
typedef unsigned int u32x4 __attribute__((ext_vector_type(4)));

// logit = (2*ab - |k|^2)/sqrt(64); exp2 domain:
// arg = ab*(2*log2e/8) - ksq*(log2e/8). Q pre-scaled by C2Q at bf16-cast,
// ksq pre-scaled by C_KSQ, stored as bf16 hi+lo pair.
#define C2Q   0.36067376f
#define C_KSQ 0.18033688f

__device__ inline f32x16 mfma32(bf16x8 a, bf16x8 b, f32x16 c) {
    return __builtin_amdgcn_mfma_f32_32x32x16_bf16(a, b, c, 0, 0, 0);
}

__device__ inline unsigned pack_bf16(float lo, float hi) {
    union { __bf16 h; unsigned short u; } a, b;
    a.h = (__bf16)lo; b.h = (__bf16)hi;
    return ((unsigned)b.u << 16) | a.u;
}

// ---------------------------------------------------------------------------
// prep_k: ktile[b][mt][ks][h][l][8] : elem = K[b][m=32mt+l][k=16ks+8h+i]
// (QK A-frag load = contiguous 1KB wave-load). ksq2 = packed bf16 {hi,lo}.
// ---------------------------------------------------------------------------
__global__ __launch_bounds__(256) void prep_k(const float* __restrict__ mk,
                                              __bf16* __restrict__ ktile,
                                              unsigned* __restrict__ ksq2) {
    const int idx = blockIdx.x * 256 + threadIdx.x;   // B*M threads
    const int b = idx / M_, m = idx % M_;
    const float* src = mk + (size_t)b * CK_ * M_ + m;
    const int mt = m >> 5, l = m & 31;
    __bf16* dstb = ktile + (size_t)b * M_ * 64 + (size_t)mt * 2048 + l * 8;
    float s = 0.f;
#pragma unroll
    for (int j = 0; j < 8; ++j) {          // octet j: ks = j>>1, h = j&1
        bf16x8 o;
#pragma unroll
        for (int i = 0; i < 8; ++i) {
            float v = src[(size_t)(8 * j + i) * M_];
            s += v * v;
            o[i] = (__bf16)v;
        }
        *(bf16x8*)(dstb + (size_t)j * 256) = o;
    }
    const float tot = s * C_KSQ;
    const float hi = (float)(__bf16)tot;
    const float lo = tot - hi;
    ksq2[idx] = pack_bf16(hi, lo);
}

// ---------------------------------------------------------------------------
// prep_v: vt[b][m16][c][16] : elem = V[b][c][m=16*m16+i].
// ---------------------------------------------------------------------------
__global__ __launch_bounds__(256) void prep_v(const float* __restrict__ mv,
                                              __bf16* __restrict__ vt) {
    const int idx = blockIdx.x * 256 + threadIdx.x;   // B*1152*CV threads
    const int c   = idx % CV_;
    const int r   = idx / CV_;
    const int m16 = r % (M_ / 16);
    const int b   = r / (M_ / 16);
    const float4* s4 = (const float4*)(mv + ((size_t)b * CV_ + c) * M_ + m16 * 16);
    const float4 a0 = s4[0], a1 = s4[1], a2 = s4[2], a3 = s4[3];
    bf16x8 o0, o1;
    o0[0]=(__bf16)a0.x; o0[1]=(__bf16)a0.y; o0[2]=(__bf16)a0.z; o0[3]=(__bf16)a0.w;
    o0[4]=(__bf16)a1.x; o0[5]=(__bf16)a1.y; o0[6]=(__bf16)a1.z; o0[7]=(__bf16)a1.w;
    o1[0]=(__bf16)a2.x; o1[1]=(__bf16)a2.y; o1[2]=(__bf16)a2.z; o1[3]=(__bf16)a2.w;
    o1[4]=(__bf16)a3.x; o1[5]=(__bf16)a3.y; o1[6]=(__bf16)a3.z; o1[7]=(__bf16)a3.w;
    __bf16* dst = vt + ((size_t)r * CV_ + c) * 16;
    *(bf16x8*)dst = o0;
    *(bf16x8*)(dst + 8) = o1;
}

// ---------------------------------------------------------------------------
// flash10: F=2 (32 q x 256 c x M/8 per wave) refit for 2 waves/SIMD.
// Register diet vs flash9 (320 -> ~240 unified peak):
//  - K: single named buffer; reloaded with K(s+1) right AFTER QK(s) issues
//    (old values dead) -> full prefetch distance at half the registers.
//  - V: 4-frag JIT batches va/vb (32 regs), reloaded mid-PV; the 4-MFMA
//    (~130 cyc matrix-pipe) group before each use covers the L1/L2 return,
//    and the second wave per SIMD covers the rest.
//  - single d (no QK-ahead pipeline) -- TLP replaces it.
// __launch_bounds__(256,2) binds the allocator at 256 unified regs.
// WRITE_SIZE is the spill canary (round-9 lesson).
// Math/layout identical to rounds 5-11 (verified absmax 0.0156).
// ---------------------------------------------------------------------------

#define LOADK(k0, k1, k2, k3, kq) do {                                        \
    k0 = *(const bf16x8*)(kp + koff);                                         \
    k1 = *(const bf16x8*)(kp + koff + 512);                                   \
    k2 = *(const bf16x8*)(kp + koff + 1024);                                  \
    k3 = *(const bf16x8*)(kp + koff + 1536);                                  \
    kq = kqp[l31];                                                            \
    kp += 2048; kqp += 32;                                                    \
} while (0)

// body for strip s: kC holds K(s) on entry; if RELOADK, kC <- K(s+1) after QK.
#define BODY(RELOADK) do {                                                    \
    /* V(s, ks0, ct0-3) issued first: in flight across QK+exp */              \
    _Pragma("unroll")                                                         \
    for (int j = 0; j < 4; ++j)                                               \
        va[j] = *(const bf16x8*)(vp + voff + j * 512);                        \
    u32x4 _a4u = { h ? 0u : kqC, 0u, 0u, 0u };                                \
    const bf16x8 _af4 = __builtin_bit_cast(bf16x8, _a4u);                     \
    f32x16 _d;                                                                \
    _Pragma("unroll") for (int r = 0; r < 16; ++r) _d[r] = 0.f;               \
    __builtin_amdgcn_s_setprio(1);                                            \
    _d = mfma32(_af4, bneg, _d);                                              \
    _d = mfma32(kC0, qf[0], _d);                                              \
    _d = mfma32(kC1, qf[1], _d);                                              \
    _d = mfma32(kC2, qf[2], _d);                                              \
    _d = mfma32(kC3, qf[3], _d);                                              \
    __builtin_amdgcn_s_setprio(0);                                            \
    if (RELOADK) LOADK(kC0, kC1, kC2, kC3, kqC);   /* K(s+1), regs dead */    \
    _Pragma("unroll")                                                         \
    for (int j = 0; j < 4; ++j)                                               \
        vb[j] = *(const bf16x8*)(vp + voff + (4 + j) * 512);                  \
    unsigned _wpk[8];                                                         \
    _Pragma("unroll")                                                         \
    for (int j = 0; j < 8; ++j) {                                             \
        const float _pa = __builtin_amdgcn_exp2f(_d[2*j]);                    \
        const float _pc = __builtin_amdgcn_exp2f(_d[2*j+1]);                  \
        den[j & 3] += _pa + _pc;                                              \
        _wpk[j] = pack_bf16(_pa, _pc);                                        \
    }                                                                         \
    bf16x8 _pb0, _pb1;                                                        \
    {                                                                         \
        unsigned _a0 = _wpk[0], _b0 = _wpk[2];                                \
        unsigned _a1 = _wpk[1], _b1 = _wpk[3];                                \
        asm volatile("v_permlane32_swap_b32 %0, %1" : "+v"(_a0), "+v"(_b0));  \
        asm volatile("v_permlane32_swap_b32 %0, %1" : "+v"(_a1), "+v"(_b1));  \
        u32x4 _pu = {_a0, _a1, _b0, _b1};                                     \
        _pb0 = __builtin_bit_cast(bf16x8, _pu);                               \
    }                                                                         \
    {                                                                         \
        unsigned _a0 = _wpk[4], _b0 = _wpk[6];                                \
        unsigned _a1 = _wpk[5], _b1 = _wpk[7];                                \
        asm volatile("v_permlane32_swap_b32 %0, %1" : "+v"(_a0), "+v"(_b0));  \
        asm volatile("v_permlane32_swap_b32 %0, %1" : "+v"(_a1), "+v"(_b1));  \
        u32x4 _pu = {_a0, _a1, _b0, _b1};                                     \
        _pb1 = __builtin_bit_cast(bf16x8, _pu);                               \
    }                                                                         \
    __builtin_amdgcn_s_setprio(1);                                            \
    _Pragma("unroll")                                                         \
    for (int j = 0; j < 4; ++j)                                               \
        acc[j] = mfma32(va[j], _pb0, acc[j]);                                 \
    __builtin_amdgcn_s_setprio(0);                                            \
    _Pragma("unroll")                                                         \
    for (int j = 0; j < 4; ++j)                                               \
        va[j] = *(const bf16x8*)(vp + VSTRIDE16 + voff + j * 512);            \
    __builtin_amdgcn_s_setprio(1);                                            \
    _Pragma("unroll")                                                         \
    for (int j = 0; j < 4; ++j)                                               \
        acc[4 + j] = mfma32(vb[j], _pb0, acc[4 + j]);                         \
    __builtin_amdgcn_s_setprio(0);                                            \
    _Pragma("unroll")                                                         \
    for (int j = 0; j < 4; ++j)                                               \
        vb[j] = *(const bf16x8*)(vp + VSTRIDE16 + voff + (4 + j) * 512);      \
    __builtin_amdgcn_s_setprio(1);                                            \
    _Pragma("unroll")                                                         \
    for (int j = 0; j < 4; ++j)                                               \
        acc[j] = mfma32(va[j], _pb1, acc[j]);                                 \
    _Pragma("unroll")                                                         \
    for (int j = 0; j < 4; ++j)                                               \
        acc[4 + j] = mfma32(vb[j], _pb1, acc[4 + j]);                         \
    __builtin_amdgcn_s_setprio(0);                                            \
    vp += 2 * VSTRIDE16;                                                      \
} while (0)

__global__ __launch_bounds__(256, 2) void flash10_kernel(const __bf16* __restrict__ ktile,
                                                         const float* __restrict__ qk,
                                                         const __bf16* __restrict__ vt,
                                                         const unsigned* __restrict__ ksq2,
                                                         __bf16* __restrict__ partO,
                                                         float* __restrict__ partD) {
    const int tid = threadIdx.x;
    const int w = tid >> 6, lane = tid & 63;
    const int l31 = lane & 31, h = lane >> 5;

    // XCD-chunked decomposition: 32 groups (cs2,s,b) x 18 blocks; a group's
    // 72 waves share one K/V-segment stream -> one XCD's L2.
    const int bid = blockIdx.x;            // 0..575
    const int xcd = bid & 7;
    const int ixc = bid >> 3;              // 0..71
    const int grp = ixc / 18;              // 0..3
    const int blk = ixc % 18;              // 0..17
    const int G   = xcd * 4 + grp;         // 0..31
    const int cs2 = G & 1;
    const int sb  = G >> 1;                // 0..15
    const int s   = sb & 7, b = sb >> 3;
    const int nt  = blk * 4 + w;           // 0..71

    const int n0 = nt * 32;
    const int cw = cs2 * 256;
    const int m_base = s * MSEG;

    // lane-invariant load offsets (elements), computed ONCE
    const int koff = (h * 32 + l31) * 8;
    const int voff = (cw + l31) * 16 + 8 * h;

    // Q' B-frags: col = n0+l31, k = 16ks+8h+i, scaled by C2Q
    const float* qkb = qk + (size_t)b * CK_ * N_;
    bf16x8 qf[4];
#pragma unroll
    for (int ks = 0; ks < 4; ++ks)
#pragma unroll
      for (int i = 0; i < 8; ++i)
        qf[ks][i] = (__bf16)(qkb[(size_t)(16*ks + 8*h + i) * N_ + (n0 + l31)] * C2Q);

    // constant B-frag: -1.0bf16 at k slots {0,1}
    const u32x4 bneg_u = {0xBF80BF80u, 0u, 0u, 0u};
    const bf16x8 bneg = __builtin_bit_cast(bf16x8, bneg_u);

    // wave-uniform stream pointers, advanced by constant strides (SALU)
    const __bf16*   kp  = ktile + (size_t)b * M_ * 64 + (size_t)m_base * 64;
    const unsigned* kqp = ksq2  + (size_t)b * M_ + m_base;
    const __bf16*   vp  = vt    + (size_t)b * M_ * CV_ + (size_t)m_base * CV_;

    f32x16 acc[8];
#pragma unroll
    for (int ct = 0; ct < 8; ++ct)
#pragma unroll
      for (int r = 0; r < 16; ++r) acc[ct][r] = 0.f;
    float den[4] = {0.f, 0.f, 0.f, 0.f};

    bf16x8 kC0, kC1, kC2, kC3;
    unsigned kqC;
    bf16x8 va[4], vb[4];

    // prologue: K(0)
    LOADK(kC0, kC1, kC2, kC3, kqC);

    for (int ms = 0; ms < MSEG / 32 - 1; ++ms)        // strips 0..70
        BODY(1);
    BODY(0);                                          // strip 71, no K reload

    // denominator: lane holds sum over its 16 m-rows; add other half
    float dsum = (den[0] + den[1]) + (den[2] + den[3]);
    dsum += __shfl_xor(dsum, 32);
    if (cs2 == 0 && lane < 32)
        partD[(size_t)(s * B_ + b) * N_ + n0 + l31] = dsum;

    // unnormalized partial O in bf16: c = cw + 32ct + (r&3)+8*(r>>2)+4h
    __bf16* po = partO + (((size_t)(s * B_ + b) * CV_ + cw) * N_) + n0 + l31;
#pragma unroll
    for (int ct = 0; ct < 8; ++ct)
#pragma unroll
      for (int r = 0; r < 16; ++r) {
        const int crow = 32*ct + (r & 3) + 8*(r >> 2) + 4*h;
        po[(size_t)crow * N_] = (__bf16)acc[ct][r];
      }
}

// ---------------------------------------------------------------------------
// reduce: mem[b][c][n] = sum_s partO / sum_s partD  -> d_out channels 0..511
// ---------------------------------------------------------------------------
__global__ __launch_bounds__(256) void reduce_kernel(const __bf16* __restrict__ partO,
                                                     const float* __restrict__ partD,
                                                     float* __restrict__ out) {
    const int idx = blockIdx.x * 256 + threadIdx.x;   // B*CV*(N/8) threads
    const int n8 = idx % (N_ / 8);
    const int c  = (idx / (N_ / 8)) % CV_;
    const int b  = idx / ((N_ / 8) * CV_);
    float o[8] = {0,0,0,0,0,0,0,0};
    float dd[8] = {0,0,0,0,0,0,0,0};
#pragma unroll
    for (int s = 0; s < SSPLIT; ++s) {
        const bf16x8 ov = *(const bf16x8*)(partO + (((size_t)(s*B_+b)*CV_ + c) * N_) + n8*8);
        const float4 d0 = *(const float4*)(partD + (size_t)(s*B_+b)*N_ + n8*8);
        const float4 d1 = *(const float4*)(partD + (size_t)(s*B_+b)*N_ + n8*8 + 4);
#pragma unroll
        for (int j = 0; j < 8; ++j) o[j] += (float)ov[j];
        dd[0]+=d0.x; dd[1]+=d0.y; dd[2]+=d0.z; dd[3]+=d0.w;
        dd[4]+=d1.x; dd[5]+=d1.y; dd[6]+=d1.z; dd[7]+=d1.w;
    }
    float* op = out + ((size_t)b * (2*CV_) + c) * N_ + n8*8;
#pragma unroll
    for (int j = 0; j < 8; ++j) op[j] = o[j] / dd[j];
}

// ---------------------------------------------------------------------------
// conv_r: R_j[cc][b][p] = sum_{c in chunk cc} in[c][p] * w[c][j]
// ---------------------------------------------------------------------------
__global__ __launch_bounds__(256) void conv_r_kernel(const float* __restrict__ outf,
                                                     const float* __restrict__ qv,
                                                     const float* __restrict__ mask,
                                                     const float* __restrict__ cw,
                                                     float* __restrict__ Rp) {
    const int p  = blockIdx.x * 256 + threadIdx.x;   // 0..N-1
    const int cc = blockIdx.y;                        // 0..8
    const int b  = blockIdx.z;
    float r[9] = {0,0,0,0,0,0,0,0,0};
    if (cc < 8) {
        const float* src = (cc < 4) ? outf + ((size_t)b * (2*CV_) + cc * 128) * N_
                                    : qv   + ((size_t)b * CV_ + (cc - 4) * 128) * N_;
        const float* wb = cw + (size_t)cc * 128 * 9;
        for (int c = 0; c < 128; ++c) {
            const float v = src[(size_t)c * N_ + p];
#pragma unroll
            for (int j = 0; j < 9; ++j) r[j] += v * wb[c * 9 + j];
        }
    } else {
        const float v = mask[(size_t)b * N_ + p];
#pragma unroll
        for (int j = 0; j < 9; ++j) r[j] = v * cw[1024 * 9 + j];
    }
#pragma unroll
    for (int j = 0; j < 9; ++j)
        Rp[(((size_t)cc * 9 + j) * B_ + b) * N_ + p] = r[j];
}

// ---------------------------------------------------------------------------
// gate: gate[b][p] = sigmoid( sum_j sum_cc Rp[cc][j][b][neighbor_j(p)] + bias )
// ---------------------------------------------------------------------------
__global__ __launch_bounds__(256) void gate_kernel(const float* __restrict__ Rp,
                                                   const float* __restrict__ cbias,
                                                   float* __restrict__ gate_ws) {
    const int p = blockIdx.x * 256 + threadIdx.x;    // 0..N-1
    const int b = blockIdx.y;
    const int y = p / W_, x = p % W_;
    float sum = cbias[0];
#pragma unroll
    for (int dy = -1; dy <= 1; ++dy) {
        const int yy = y + dy;
        if (yy < 0 || yy >= H_) continue;
#pragma unroll
        for (int dx = -1; dx <= 1; ++dx) {
            const int xx = x + dx;
            if (xx < 0 || xx >= W_) continue;
            const int j = (dy + 1) * 3 + (dx + 1);
            const int q = yy * W_ + xx;
#pragma unroll
            for (int cc = 0; cc < 9; ++cc)
                sum += Rp[(((size_t)cc * 9 + j) * B_ + b) * N_ + q];
        }
    }
    gate_ws[(size_t)b * N_ + p] = 1.f / (1.f + __builtin_amdgcn_exp2f(-sum * 1.44269504f));
}

// ---------------------------------------------------------------------------
// finalize: out[b][ch][n] = (ch<512 ? mem : qv) * gate[b][n]
// ---------------------------------------------------------------------------
__global__ __launch_bounds__(256) void finalize_kernel(const float* __restrict__ qv,
                                                       const float* __restrict__ gate_ws,
                                                       float* __restrict__ out) {
    const int idx = blockIdx.x * 256 + threadIdx.x;
    const int n4 = N_ / 4;
    const int pos4 = idx % n4;
    const int row  = idx / n4;
    const int b = row >> 10, ch = row & 1023;
    const float4 gv = *(const float4*)(gate_ws + (size_t)b * N_ + pos4 * 4);
    float* op = out + (size_t)row * N_ + pos4 * 4;
    float4 v;
    if (ch < CV_) v = *(const float4*)op;
    else          v = *(const float4*)(qv + ((size_t)b * CV_ + (ch - CV_)) * N_ + pos4 * 4);
    v.x *= gv.x; v.y *= gv.y; v.z *= gv.z; v.w *= gv.w;
    *(float4*)op = v;
}

// ===========================================================================
extern "C" void kernel_launch(void* const* d_in, const int* in_sizes, int n_in,
                              void* d_out, int out_size, void* d_ws, size_t ws_size,
                              hipStream_t stream) {
    (void)in_sizes; (void)n_in; (void)out_size; (void)ws_size;
    const float* mk    = (const float*)d_in[0];
    const float* qk    = (const float*)d_in[1];
    const float* mv    = (const float*)d_in[2];
    const float* qv    = (const float*)d_in[3];
    const float* mask  = (const float*)d_in[4];
    const float* cw    = (const float*)d_in[5];
    const float* cbias = (const float*)d_in[6];
    float* outf = (float*)d_out;

    // workspace layout (bytes) — total 80,529,408, byte-identical to rounds 3-11
    const size_t kbf_b   = (size_t)B_ * M_ * 64 * 2;             //  4,718,592 (ktile; reused as Rp)
    const size_t vbf_b   = (size_t)B_ * CV_ * M_ * 2;            // 37,748,736 (vt)
    const size_t ksq_b   = (size_t)B_ * M_ * 4;                  //    147,456 (packed u32 hi/lo)
    const size_t partO_b = (size_t)SSPLIT * B_ * CV_ * N_ * 2;   // 37,748,736 (bf16)
    const size_t partD_b = (size_t)SSPLIT * B_ * N_ * 4;         //    147,456

    char* pw = (char*)d_ws;
    __bf16* ktile = (__bf16*)pw;
    float*  Rp    = (float*)pw;            // overlays ktile (dead after flash10)
    pw += kbf_b;
    __bf16* vt    = (__bf16*)pw;           pw += vbf_b;
    unsigned* ksq2 = (unsigned*)pw;        pw += ksq_b;
    __bf16* partO = (__bf16*)pw;           pw += partO_b;
    float*  partD = (float*)pw;            pw += partD_b;
    float*  gate_ws = (float*)pw;

    prep_k<<<dim3(B_ * M_ / 256), 256, 0, stream>>>(mk, ktile, ksq2);
    prep_v<<<dim3((size_t)B_ * (M_ / 16) * CV_ / 256, 1, 1), 256, 0, stream>>>(mv, vt);
    flash10_kernel<<<dim3(576), 256, 0, stream>>>(ktile, qk, vt, ksq2, partO, partD);
    reduce_kernel<<<dim3(B_ * CV_ * (N_ / 8) / 256), 256, 0, stream>>>(partO, partD, outf);
    conv_r_kernel<<<dim3(N_ / 256, 9, B_), 256, 0, stream>>>(outf, qv, mask, cw, Rp);
    gate_kernel<<<dim3(N_ / 256, B_), 256, 0, stream>>>(Rp, cbias, gate_ws);
    finalize_kernel<<<dim3((B_ * 2 * CV_ * N_ / 4) / 256), 256, 0, stream>>>(qv, gate_ws, outf);
}

// Round 13
// 234.482 us; speedup vs baseline: 1.0571x; 1.0571x over previous
//
#include <hip/hip_runtime.h>

// Problem constants (fixed by setup_inputs)
#define B_  2
#define CK_ 64
#define CV_ 512
#define H_  48
#define W_  48
#define M_  18432   // T*H*W
#define N_  2304    // H*W

#define SSPLIT 8
#define MSEG   (M_ / SSPLIT)   // 2304
#define VSTRIDE16 (CV_ * 16)   // elems per m16 block in vt = 8192

typedef __bf16 bf16x8 __attribute__((ext_vector_type(8)));
typedef float  f32x4  __attribute__((ext_vector_type(4)));
typedef float  f32x16 __attribute__((ext_vector_type(16)));
typedef unsigned int u32x4 __attribute__((ext_vector_type(4)));

// logit = (2*ab - |k|^2)/sqrt(64); exp2 domain:
// arg = ab*(2*log2e/8) - ksq*(log2e/8). Q pre-scaled by C2Q at bf16-cast,
// ksq pre-scaled by C_KSQ, stored as bf16 hi+lo pair.
#define C2Q   0.36067376f
#define C_KSQ 0.18033688f

__device__ inline f32x16 mfma32(bf16x8 a, bf16x8 b, f32x16 c) {
    return __builtin_amdgcn_mfma_f32_32x32x16_bf16(a, b, c, 0, 0, 0);
}

__device__ inline unsigned pack_bf16(float lo, float hi) {
    union { __bf16 h; unsigned short u; } a, b;
    a.h = (__bf16)lo; b.h = (__bf16)hi;
    return ((unsigned)b.u << 16) | a.u;
}

// async global->LDS, 16B per lane; LDS dest = uniform base + lane*16 (HW).
__device__ __forceinline__ void gload_lds16(const __bf16* g, __bf16* l) {
    __builtin_amdgcn_global_load_lds(
        (const __attribute__((address_space(1))) void*)g,
        (__attribute__((address_space(3))) void*)l,
        16, 0, 0);
}

// ---------------------------------------------------------------------------
// prep_k: ktile[b][mt][ks][h][l][8] : elem = K[b][m=32mt+l][k=16ks+8h+i]
// (QK A-frag load = contiguous 1KB wave-load). ksq2 = packed bf16 {hi,lo}.
// ---------------------------------------------------------------------------
__global__ __launch_bounds__(256) void prep_k(const float* __restrict__ mk,
                                              __bf16* __restrict__ ktile,
                                              unsigned* __restrict__ ksq2) {
    const int idx = blockIdx.x * 256 + threadIdx.x;   // B*M threads
    const int b = idx / M_, m = idx % M_;
    const float* src = mk + (size_t)b * CK_ * M_ + m;
    const int mt = m >> 5, l = m & 31;
    __bf16* dstb = ktile + (size_t)b * M_ * 64 + (size_t)mt * 2048 + l * 8;
    float s = 0.f;
#pragma unroll
    for (int j = 0; j < 8; ++j) {          // octet j: ks = j>>1, h = j&1
        bf16x8 o;
#pragma unroll
        for (int i = 0; i < 8; ++i) {
            float v = src[(size_t)(8 * j + i) * M_];
            s += v * v;
            o[i] = (__bf16)v;
        }
        *(bf16x8*)(dstb + (size_t)j * 256) = o;
    }
    const float tot = s * C_KSQ;
    const float hi = (float)(__bf16)tot;
    const float lo = tot - hi;
    ksq2[idx] = pack_bf16(hi, lo);
}

// ---------------------------------------------------------------------------
// prep_v: vt[b][m16][c][16] : elem = V[b][c][m=16*m16+i].
// ---------------------------------------------------------------------------
__global__ __launch_bounds__(256) void prep_v(const float* __restrict__ mv,
                                              __bf16* __restrict__ vt) {
    const int idx = blockIdx.x * 256 + threadIdx.x;   // B*1152*CV threads
    const int c   = idx % CV_;
    const int r   = idx / CV_;
    const int m16 = r % (M_ / 16);
    const int b   = r / (M_ / 16);
    const float4* s4 = (const float4*)(mv + ((size_t)b * CV_ + c) * M_ + m16 * 16);
    const float4 a0 = s4[0], a1 = s4[1], a2 = s4[2], a3 = s4[3];
    bf16x8 o0, o1;
    o0[0]=(__bf16)a0.x; o0[1]=(__bf16)a0.y; o0[2]=(__bf16)a0.z; o0[3]=(__bf16)a0.w;
    o0[4]=(__bf16)a1.x; o0[5]=(__bf16)a1.y; o0[6]=(__bf16)a1.z; o0[7]=(__bf16)a1.w;
    o1[0]=(__bf16)a2.x; o1[1]=(__bf16)a2.y; o1[2]=(__bf16)a2.z; o1[3]=(__bf16)a2.w;
    o1[4]=(__bf16)a3.x; o1[5]=(__bf16)a3.y; o1[6]=(__bf16)a3.z; o1[7]=(__bf16)a3.w;
    __bf16* dst = vt + ((size_t)r * CV_ + c) * 16;
    *(bf16x8*)dst = o0;
    *(bf16x8*)(dst + 8) = o1;
}

// ---------------------------------------------------------------------------
// flash11: flash10 + LDS-shared, double-buffered V staging.
// The 4 waves of a block consume IDENTICAL V (and K); V strips (16KB) are
// staged once per block via global_load_lds into Vlds[2] (linear copy of the
// vt tile layout -> ds_read_b128 fragments are the canonical contiguous-16B
// pattern, conflict-free). One __syncthreads per strip; stage(s+1) issued
// right after it -> a full strip (~1000 cyc) of flight time. K stays in
// registers (reload-after-QK, one strip ahead). ~248 unified regs,
// 2 waves/SIMD + 32KB LDS -> 2 blocks/CU.
// Math/layout identical to rounds 5-12 (verified absmax 0.0156).
// ---------------------------------------------------------------------------

#define LOADK(k0, k1, k2, k3, kq) do {                                        \
    k0 = *(const bf16x8*)(kp + koff);                                         \
    k1 = *(const bf16x8*)(kp + koff + 512);                                   \
    k2 = *(const bf16x8*)(kp + koff + 1024);                                  \
    k3 = *(const bf16x8*)(kp + koff + 1536);                                  \
    kq = kqp[l31];                                                            \
    kp += 2048; kqp += 32;                                                    \
} while (0)

// stage next strip's V (16KB = 16 x 1KB pieces, 4 per wave) into LDS
#define STAGEV(vnxt) do {                                                     \
    _Pragma("unroll")                                                         \
    for (int i = 0; i < 4; ++i) {                                             \
        const int j = i * 4 + w;                                              \
        const int chunk = j >> 3, off = j & 7;                                \
        gload_lds16(vps + chunk * VSTRIDE16 + cwoff + off * 512 + laneoff,    \
                    (vnxt) + chunk * 4096 + off * 512);                       \
    }                                                                         \
    vps += 2 * VSTRIDE16;                                                     \
} while (0)

// body for strip s: V(s) in LDS vcur (staged last strip, fenced by the top
// barrier); stage V(s+1) -> vnxt; kC holds K(s), reloaded with K(s+1) after QK.
#define BODY(vcur, vnxt, STAGE, RELOADK) do {                                 \
    __syncthreads();                                                          \
    if (STAGE) STAGEV(vnxt);                                                  \
    u32x4 _a4u = { h ? 0u : kqC, 0u, 0u, 0u };                                \
    const bf16x8 _af4 = __builtin_bit_cast(bf16x8, _a4u);                     \
    f32x16 _d;                                                                \
    _Pragma("unroll") for (int r = 0; r < 16; ++r) _d[r] = 0.f;               \
    __builtin_amdgcn_s_setprio(1);                                            \
    _d = mfma32(_af4, bneg, _d);                                              \
    _d = mfma32(kC0, qf[0], _d);                                              \
    _d = mfma32(kC1, qf[1], _d);                                              \
    _d = mfma32(kC2, qf[2], _d);                                              \
    _d = mfma32(kC3, qf[3], _d);                                              \
    __builtin_amdgcn_s_setprio(0);                                            \
    if (RELOADK) LOADK(kC0, kC1, kC2, kC3, kqC);   /* K(s+1), regs dead */    \
    unsigned _wpk[8];                                                         \
    _Pragma("unroll")                                                         \
    for (int j = 0; j < 8; ++j) {                                             \
        const float _pa = __builtin_amdgcn_exp2f(_d[2*j]);                    \
        const float _pc = __builtin_amdgcn_exp2f(_d[2*j+1]);                  \
        den[j & 3] += _pa + _pc;                                              \
        _wpk[j] = pack_bf16(_pa, _pc);                                        \
    }                                                                         \
    bf16x8 _pb0, _pb1;                                                        \
    {                                                                         \
        unsigned _a0 = _wpk[0], _b0 = _wpk[2];                                \
        unsigned _a1 = _wpk[1], _b1 = _wpk[3];                                \
        asm volatile("v_permlane32_swap_b32 %0, %1" : "+v"(_a0), "+v"(_b0));  \
        asm volatile("v_permlane32_swap_b32 %0, %1" : "+v"(_a1), "+v"(_b1));  \
        u32x4 _pu = {_a0, _a1, _b0, _b1};                                     \
        _pb0 = __builtin_bit_cast(bf16x8, _pu);                               \
    }                                                                         \
    {                                                                         \
        unsigned _a0 = _wpk[4], _b0 = _wpk[6];                                \
        unsigned _a1 = _wpk[5], _b1 = _wpk[7];                                \
        asm volatile("v_permlane32_swap_b32 %0, %1" : "+v"(_a0), "+v"(_b0));  \
        asm volatile("v_permlane32_swap_b32 %0, %1" : "+v"(_a1), "+v"(_b1));  \
        u32x4 _pu = {_a0, _a1, _b0, _b1};                                     \
        _pb1 = __builtin_bit_cast(bf16x8, _pu);                               \
    }                                                                         \
    /* PV from LDS: ks0 (elem 0..4095), ks1 (elem 4096..8191) */              \
    _Pragma("unroll")                                                         \
    for (int j = 0; j < 4; ++j)                                               \
        va[j] = *(const bf16x8*)((vcur) + j * 512 + vloff);                   \
    _Pragma("unroll")                                                         \
    for (int j = 0; j < 4; ++j)                                               \
        vb[j] = *(const bf16x8*)((vcur) + (4 + j) * 512 + vloff);             \
    __builtin_amdgcn_s_setprio(1);                                            \
    _Pragma("unroll")                                                         \
    for (int j = 0; j < 4; ++j)                                               \
        acc[j] = mfma32(va[j], _pb0, acc[j]);                                 \
    __builtin_amdgcn_s_setprio(0);                                            \
    _Pragma("unroll")                                                         \
    for (int j = 0; j < 4; ++j)                                               \
        va[j] = *(const bf16x8*)((vcur) + 4096 + j * 512 + vloff);            \
    __builtin_amdgcn_s_setprio(1);                                            \
    _Pragma("unroll")                                                         \
    for (int j = 0; j < 4; ++j)                                               \
        acc[4 + j] = mfma32(vb[j], _pb0, acc[4 + j]);                         \
    __builtin_amdgcn_s_setprio(0);                                            \
    _Pragma("unroll")                                                         \
    for (int j = 0; j < 4; ++j)                                               \
        vb[j] = *(const bf16x8*)((vcur) + 4096 + (4 + j) * 512 + vloff);      \
    __builtin_amdgcn_s_setprio(1);                                            \
    _Pragma("unroll")                                                         \
    for (int j = 0; j < 4; ++j)                                               \
        acc[j] = mfma32(va[j], _pb1, acc[j]);                                 \
    _Pragma("unroll")                                                         \
    for (int j = 0; j < 4; ++j)                                               \
        acc[4 + j] = mfma32(vb[j], _pb1, acc[4 + j]);                         \
    __builtin_amdgcn_s_setprio(0);                                            \
} while (0)

__global__ __launch_bounds__(256, 2) void flash11_kernel(const __bf16* __restrict__ ktile,
                                                         const float* __restrict__ qk,
                                                         const __bf16* __restrict__ vt,
                                                         const unsigned* __restrict__ ksq2,
                                                         __bf16* __restrict__ partO,
                                                         float* __restrict__ partD) {
    const int tid = threadIdx.x;
    const int w = tid >> 6, lane = tid & 63;
    const int l31 = lane & 31, h = lane >> 5;

    // XCD-chunked decomposition: 32 groups (cs2,s,b) x 18 blocks; a group's
    // 72 waves share one K/V-segment stream -> one XCD's L2.
    const int bid = blockIdx.x;            // 0..575
    const int xcd = bid & 7;
    const int ixc = bid >> 3;              // 0..71
    const int grp = ixc / 18;              // 0..3
    const int blk = ixc % 18;              // 0..17
    const int G   = xcd * 4 + grp;         // 0..31
    const int cs2 = G & 1;
    const int sb  = G >> 1;                // 0..15
    const int s   = sb & 7, b = sb >> 3;
    const int nt  = blk * 4 + w;           // 0..71

    const int n0 = nt * 32;
    const int cw = cs2 * 256;
    const int m_base = s * MSEG;

    // lane-invariant offsets (elements), computed ONCE
    const int koff    = (h * 32 + l31) * 8;
    const int vloff   = l31 * 16 + 8 * h;     // within-chunk LDS frag offset
    const int cwoff   = cw * 16;              // channel-window offset in vt chunk
    const int laneoff = lane * 8;             // 16B per lane for staging

    // shared V strip buffers: linear copy of vt chunk layout, 2 x 16KB
    __shared__ __align__(16) __bf16 Vlds[2][8192];

    // Q' B-frags: col = n0+l31, k = 16ks+8h+i, scaled by C2Q
    const float* qkb = qk + (size_t)b * CK_ * N_;
    bf16x8 qf[4];
#pragma unroll
    for (int ks = 0; ks < 4; ++ks)
#pragma unroll
      for (int i = 0; i < 8; ++i)
        qf[ks][i] = (__bf16)(qkb[(size_t)(16*ks + 8*h + i) * N_ + (n0 + l31)] * C2Q);

    // constant B-frag: -1.0bf16 at k slots {0,1}
    const u32x4 bneg_u = {0xBF80BF80u, 0u, 0u, 0u};
    const bf16x8 bneg = __builtin_bit_cast(bf16x8, bneg_u);

    // wave-uniform stream pointers, advanced by constant strides (SALU)
    const __bf16*   kp  = ktile + (size_t)b * M_ * 64 + (size_t)m_base * 64;
    const unsigned* kqp = ksq2  + (size_t)b * M_ + m_base;
    const __bf16*   vps = vt    + (size_t)b * M_ * CV_ + (size_t)m_base * CV_;

    f32x16 acc[8];
#pragma unroll
    for (int ct = 0; ct < 8; ++ct)
#pragma unroll
      for (int r = 0; r < 16; ++r) acc[ct][r] = 0.f;
    float den[4] = {0.f, 0.f, 0.f, 0.f};

    bf16x8 kC0, kC1, kC2, kC3;
    unsigned kqC;
    bf16x8 va[4], vb[4];

    // prologue: K(0) regs + V(0) staged into buf0
    LOADK(kC0, kC1, kC2, kC3, kqC);
    STAGEV(&Vlds[0][0]);

    for (int mss = 0; mss < 35; ++mss) {              // strips 0..69
        BODY(&Vlds[0][0], &Vlds[1][0], 1, 1);
        BODY(&Vlds[1][0], &Vlds[0][0], 1, 1);
    }
    BODY(&Vlds[0][0], &Vlds[1][0], 1, 1);             // strip 70 (stages 71)
    BODY(&Vlds[1][0], &Vlds[0][0], 0, 0);             // strip 71

    // denominator: lane holds sum over its 16 m-rows; add other half
    float dsum = (den[0] + den[1]) + (den[2] + den[3]);
    dsum += __shfl_xor(dsum, 32);
    if (cs2 == 0 && lane < 32)
        partD[(size_t)(s * B_ + b) * N_ + n0 + l31] = dsum;

    // unnormalized partial O in bf16: c = cw + 32ct + (r&3)+8*(r>>2)+4h
    __bf16* po = partO + (((size_t)(s * B_ + b) * CV_ + cw) * N_) + n0 + l31;
#pragma unroll
    for (int ct = 0; ct < 8; ++ct)
#pragma unroll
      for (int r = 0; r < 16; ++r) {
        const int crow = 32*ct + (r & 3) + 8*(r >> 2) + 4*h;
        po[(size_t)crow * N_] = (__bf16)acc[ct][r];
      }
}

// ---------------------------------------------------------------------------
// reduce: mem[b][c][n] = sum_s partO / sum_s partD  -> d_out channels 0..511
// ---------------------------------------------------------------------------
__global__ __launch_bounds__(256) void reduce_kernel(const __bf16* __restrict__ partO,
                                                     const float* __restrict__ partD,
                                                     float* __restrict__ out) {
    const int idx = blockIdx.x * 256 + threadIdx.x;   // B*CV*(N/8) threads
    const int n8 = idx % (N_ / 8);
    const int c  = (idx / (N_ / 8)) % CV_;
    const int b  = idx / ((N_ / 8) * CV_);
    float o[8] = {0,0,0,0,0,0,0,0};
    float dd[8] = {0,0,0,0,0,0,0,0};
#pragma unroll
    for (int s = 0; s < SSPLIT; ++s) {
        const bf16x8 ov = *(const bf16x8*)(partO + (((size_t)(s*B_+b)*CV_ + c) * N_) + n8*8);
        const float4 d0 = *(const float4*)(partD + (size_t)(s*B_+b)*N_ + n8*8);
        const float4 d1 = *(const float4*)(partD + (size_t)(s*B_+b)*N_ + n8*8 + 4);
#pragma unroll
        for (int j = 0; j < 8; ++j) o[j] += (float)ov[j];
        dd[0]+=d0.x; dd[1]+=d0.y; dd[2]+=d0.z; dd[3]+=d0.w;
        dd[4]+=d1.x; dd[5]+=d1.y; dd[6]+=d1.z; dd[7]+=d1.w;
    }
    float* op = out + ((size_t)b * (2*CV_) + c) * N_ + n8*8;
#pragma unroll
    for (int j = 0; j < 8; ++j) op[j] = o[j] / dd[j];
}

// ---------------------------------------------------------------------------
// conv_r: R_j[cc][b][p] = sum_{c in chunk cc} in[c][p] * w[c][j]
// ---------------------------------------------------------------------------
__global__ __launch_bounds__(256) void conv_r_kernel(const float* __restrict__ outf,
                                                     const float* __restrict__ qv,
                                                     const float* __restrict__ mask,
                                                     const float* __restrict__ cw,
                                                     float* __restrict__ Rp) {
    const int p  = blockIdx.x * 256 + threadIdx.x;   // 0..N-1
    const int cc = blockIdx.y;                        // 0..8
    const int b  = blockIdx.z;
    float r[9] = {0,0,0,0,0,0,0,0,0};
    if (cc < 8) {
        const float* src = (cc < 4) ? outf + ((size_t)b * (2*CV_) + cc * 128) * N_
                                    : qv   + ((size_t)b * CV_ + (cc - 4) * 128) * N_;
        const float* wb = cw + (size_t)cc * 128 * 9;
        for (int c = 0; c < 128; ++c) {
            const float v = src[(size_t)c * N_ + p];
#pragma unroll
            for (int j = 0; j < 9; ++j) r[j] += v * wb[c * 9 + j];
        }
    } else {
        const float v = mask[(size_t)b * N_ + p];
#pragma unroll
        for (int j = 0; j < 9; ++j) r[j] = v * cw[1024 * 9 + j];
    }
#pragma unroll
    for (int j = 0; j < 9; ++j)
        Rp[(((size_t)cc * 9 + j) * B_ + b) * N_ + p] = r[j];
}

// ---------------------------------------------------------------------------
// gate: gate[b][p] = sigmoid( sum_j sum_cc Rp[cc][j][b][neighbor_j(p)] + bias )
// ---------------------------------------------------------------------------
__global__ __launch_bounds__(256) void gate_kernel(const float* __restrict__ Rp,
                                                   const float* __restrict__ cbias,
                                                   float* __restrict__ gate_ws) {
    const int p = blockIdx.x * 256 + threadIdx.x;    // 0..N-1
    const int b = blockIdx.y;
    const int y = p / W_, x = p % W_;
    float sum = cbias[0];
#pragma unroll
    for (int dy = -1; dy <= 1; ++dy) {
        const int yy = y + dy;
        if (yy < 0 || yy >= H_) continue;
#pragma unroll
        for (int dx = -1; dx <= 1; ++dx) {
            const int xx = x + dx;
            if (xx < 0 || xx >= W_) continue;
            const int j = (dy + 1) * 3 + (dx + 1);
            const int q = yy * W_ + xx;
#pragma unroll
            for (int cc = 0; cc < 9; ++cc)
                sum += Rp[(((size_t)cc * 9 + j) * B_ + b) * N_ + q];
        }
    }
    gate_ws[(size_t)b * N_ + p] = 1.f / (1.f + __builtin_amdgcn_exp2f(-sum * 1.44269504f));
}

// ---------------------------------------------------------------------------
// finalize: out[b][ch][n] = (ch<512 ? mem : qv) * gate[b][n]
// ---------------------------------------------------------------------------
__global__ __launch_bounds__(256) void finalize_kernel(const float* __restrict__ qv,
                                                       const float* __restrict__ gate_ws,
                                                       float* __restrict__ out) {
    const int idx = blockIdx.x * 256 + threadIdx.x;
    const int n4 = N_ / 4;
    const int pos4 = idx % n4;
    const int row  = idx / n4;
    const int b = row >> 10, ch = row & 1023;
    const float4 gv = *(const float4*)(gate_ws + (size_t)b * N_ + pos4 * 4);
    float* op = out + (size_t)row * N_ + pos4 * 4;
    float4 v;
    if (ch < CV_) v = *(const float4*)op;
    else          v = *(const float4*)(qv + ((size_t)b * CV_ + (ch - CV_)) * N_ + pos4 * 4);
    v.x *= gv.x; v.y *= gv.y; v.z *= gv.z; v.w *= gv.w;
    *(float4*)op = v;
}

// ===========================================================================
extern "C" void kernel_launch(void* const* d_in, const int* in_sizes, int n_in,
                              void* d_out, int out_size, void* d_ws, size_t ws_size,
                              hipStream_t stream) {
    (void)in_sizes; (void)n_in; (void)out_size; (void)ws_size;
    const float* mk    = (const float*)d_in[0];
    const float* qk    = (const float*)d_in[1];
    const float* mv    = (const float*)d_in[2];
    const float* qv    = (const float*)d_in[3];
    const float* mask  = (const float*)d_in[4];
    const float* cw    = (const float*)d_in[5];
    const float* cbias = (const float*)d_in[6];
    float* outf = (float*)d_out;

    // workspace layout (bytes) — total 80,529,408, byte-identical to rounds 3-12
    const size_t kbf_b   = (size_t)B_ * M_ * 64 * 2;             //  4,718,592 (ktile; reused as Rp)
    const size_t vbf_b   = (size_t)B_ * CV_ * M_ * 2;            // 37,748,736 (vt)
    const size_t ksq_b   = (size_t)B_ * M_ * 4;                  //    147,456 (packed u32 hi/lo)
    const size_t partO_b = (size_t)SSPLIT * B_ * CV_ * N_ * 2;   // 37,748,736 (bf16)
    const size_t partD_b = (size_t)SSPLIT * B_ * N_ * 4;         //    147,456

    char* pw = (char*)d_ws;
    __bf16* ktile = (__bf16*)pw;
    float*  Rp    = (float*)pw;            // overlays ktile (dead after flash11)
    pw += kbf_b;
    __bf16* vt    = (__bf16*)pw;           pw += vbf_b;
    unsigned* ksq2 = (unsigned*)pw;        pw += ksq_b;
    __bf16* partO = (__bf16*)pw;           pw += partO_b;
    float*  partD = (float*)pw;            pw += partD_b;
    float*  gate_ws = (float*)pw;

    prep_k<<<dim3(B_ * M_ / 256), 256, 0, stream>>>(mk, ktile, ksq2);
    prep_v<<<dim3((size_t)B_ * (M_ / 16) * CV_ / 256, 1, 1), 256, 0, stream>>>(mv, vt);
    flash11_kernel<<<dim3(576), 256, 0, stream>>>(ktile, qk, vt, ksq2, partO, partD);
    reduce_kernel<<<dim3(B_ * CV_ * (N_ / 8) / 256), 256, 0, stream>>>(partO, partD, outf);
    conv_r_kernel<<<dim3(N_ / 256, 9, B_), 256, 0, stream>>>(outf, qv, mask, cw, Rp);
    gate_kernel<<<dim3(N_ / 256, B_), 256, 0, stream>>>(Rp, cbias, gate_ws);
    finalize_kernel<<<dim3((B_ * 2 * CV_ * N_ / 4) / 256), 256, 0, stream>>>(qv, gate_ws, outf);
}

// Round 14
// 232.741 us; speedup vs baseline: 1.0650x; 1.0075x over previous
//
#include <hip/hip_runtime.h>

// Problem constants (fixed by setup_inputs)
#define B_  2
#define CK_ 64
#define CV_ 512
#define H_  48
#define W_  48
#define M_  18432   // T*H*W
#define N_  2304    // H*W

#define SSPLIT 8
#define MSEG   (M_ / SSPLIT)   // 2304
#define VSTRIDE16 (CV_ * 16)   // elems per m16 block in vt = 8192

typedef __bf16 bf16x8 __attribute__((ext_vector_type(8)));
typedef float  f32x4  __attribute__((ext_vector_type(4)));
typedef float  f32x16 __attribute__((ext_vector_type(16)));
typedef unsigned int u32x4 __attribute__((ext_vector_type(4)));

// logit = (2*ab - |k|^2)/sqrt(64); exp2 domain:
// arg = ab*(2*log2e/8) - ksq*(log2e/8). Q pre-scaled by C2Q at bf16-cast,
// ksq pre-scaled by C_KSQ, stored as bf16 hi+lo pair.
#define C2Q   0.36067376f
#define C_KSQ 0.18033688f

__device__ inline f32x16 mfma32(bf16x8 a, bf16x8 b, f32x16 c) {
    return __builtin_amdgcn_mfma_f32_32x32x16_bf16(a, b, c, 0, 0, 0);
}

__device__ inline unsigned pack_bf16(float lo, float hi) {
    union { __bf16 h; unsigned short u; } a, b;
    a.h = (__bf16)lo; b.h = (__bf16)hi;
    return ((unsigned)b.u << 16) | a.u;
}

// async global->LDS, 16B per lane; LDS dest = uniform base + lane*16 (HW).
__device__ __forceinline__ void gload_lds16(const __bf16* g, __bf16* l) {
    __builtin_amdgcn_global_load_lds(
        (const __attribute__((address_space(1))) void*)g,
        (__attribute__((address_space(3))) void*)l,
        16, 0, 0);
}

// ---------------------------------------------------------------------------
// prep_k: ktile[b][mt][ks][h][l][8] : elem = K[b][m=32mt+l][k=16ks+8h+i]
// (QK A-frag load = contiguous 1KB wave-load). ksq2 = packed bf16 {hi,lo}.
// ---------------------------------------------------------------------------
__global__ __launch_bounds__(256) void prep_k(const float* __restrict__ mk,
                                              __bf16* __restrict__ ktile,
                                              unsigned* __restrict__ ksq2) {
    const int idx = blockIdx.x * 256 + threadIdx.x;   // B*M threads
    const int b = idx / M_, m = idx % M_;
    const float* src = mk + (size_t)b * CK_ * M_ + m;
    const int mt = m >> 5, l = m & 31;
    __bf16* dstb = ktile + (size_t)b * M_ * 64 + (size_t)mt * 2048 + l * 8;
    float s = 0.f;
#pragma unroll
    for (int j = 0; j < 8; ++j) {          // octet j: ks = j>>1, h = j&1
        bf16x8 o;
#pragma unroll
        for (int i = 0; i < 8; ++i) {
            float v = src[(size_t)(8 * j + i) * M_];
            s += v * v;
            o[i] = (__bf16)v;
        }
        *(bf16x8*)(dstb + (size_t)j * 256) = o;
    }
    const float tot = s * C_KSQ;
    const float hi = (float)(__bf16)tot;
    const float lo = tot - hi;
    ksq2[idx] = pack_bf16(hi, lo);
}

// ---------------------------------------------------------------------------
// prep_v: vt[b][m16][c][16] : elem = V[b][c][m=16*m16+i].
// ---------------------------------------------------------------------------
__global__ __launch_bounds__(256) void prep_v(const float* __restrict__ mv,
                                              __bf16* __restrict__ vt) {
    const int idx = blockIdx.x * 256 + threadIdx.x;   // B*1152*CV threads
    const int c   = idx % CV_;
    const int r   = idx / CV_;
    const int m16 = r % (M_ / 16);
    const int b   = r / (M_ / 16);
    const float4* s4 = (const float4*)(mv + ((size_t)b * CV_ + c) * M_ + m16 * 16);
    const float4 a0 = s4[0], a1 = s4[1], a2 = s4[2], a3 = s4[3];
    bf16x8 o0, o1;
    o0[0]=(__bf16)a0.x; o0[1]=(__bf16)a0.y; o0[2]=(__bf16)a0.z; o0[3]=(__bf16)a0.w;
    o0[4]=(__bf16)a1.x; o0[5]=(__bf16)a1.y; o0[6]=(__bf16)a1.z; o0[7]=(__bf16)a1.w;
    o1[0]=(__bf16)a2.x; o1[1]=(__bf16)a2.y; o1[2]=(__bf16)a2.z; o1[3]=(__bf16)a2.w;
    o1[4]=(__bf16)a3.x; o1[5]=(__bf16)a3.y; o1[6]=(__bf16)a3.z; o1[7]=(__bf16)a3.w;
    __bf16* dst = vt + ((size_t)r * CV_ + c) * 16;
    *(bf16x8*)dst = o0;
    *(bf16x8*)(dst + 8) = o1;
}

// ---------------------------------------------------------------------------
// flash12: round-13 flash11 + conflict-free LDS V (source pre-swizzle).
// Round-13 read pattern (byte l31*32 + h*16) was an 8-way bank conflict
// (1.06e7 conflict cycles). Fix per rule #21: LDS dest stays linear
// (lane*16B, HW), the GLOBAL source per lane is permuted to
// (lane&31)*16 + (lane>>5)*8 elements, and the PV read offset becomes
// lane*16B linear -> dense 1024B wave reads, conflict-free.
// Also: persistent fzero as C of the first QK MFMA (kills 16 movs/strip).
// Math/layout identical to rounds 5-13 (verified absmax 0.0156).
// ---------------------------------------------------------------------------

#define LOADK(k0, k1, k2, k3, kq) do {                                        \
    k0 = *(const bf16x8*)(kp + koff);                                         \
    k1 = *(const bf16x8*)(kp + koff + 512);                                   \
    k2 = *(const bf16x8*)(kp + koff + 1024);                                  \
    k3 = *(const bf16x8*)(kp + koff + 1536);                                  \
    kq = kqp[l31];                                                            \
    kp += 2048; kqp += 32;                                                    \
} while (0)

// stage next strip's V (16KB = 16 x 1KB pieces, 4 per wave) into LDS.
// Per-lane source permuted so that linear LDS order == fragment-read order.
#define STAGEV(vnxt) do {                                                     \
    _Pragma("unroll")                                                         \
    for (int i = 0; i < 4; ++i) {                                             \
        const int j = i * 4 + w;                                              \
        const int chunk = j >> 3, off = j & 7;                                \
        gload_lds16(vps + chunk * VSTRIDE16 + cwoff + off * 512 + soff,       \
                    (vnxt) + chunk * 4096 + off * 512);                       \
    }                                                                         \
    vps += 2 * VSTRIDE16;                                                     \
} while (0)

// body for strip s: V(s) in LDS vcur (staged last strip, fenced by the top
// barrier); stage V(s+1) -> vnxt; kC holds K(s), reloaded with K(s+1) after QK.
#define BODY(vcur, vnxt, STAGE, RELOADK) do {                                 \
    __syncthreads();                                                          \
    if (STAGE) STAGEV(vnxt);                                                  \
    u32x4 _a4u = { h ? 0u : kqC, 0u, 0u, 0u };                                \
    const bf16x8 _af4 = __builtin_bit_cast(bf16x8, _a4u);                     \
    __builtin_amdgcn_s_setprio(1);                                            \
    f32x16 _d = mfma32(_af4, bneg, fzero);                                    \
    _d = mfma32(kC0, qf[0], _d);                                              \
    _d = mfma32(kC1, qf[1], _d);                                              \
    _d = mfma32(kC2, qf[2], _d);                                              \
    _d = mfma32(kC3, qf[3], _d);                                              \
    __builtin_amdgcn_s_setprio(0);                                            \
    if (RELOADK) LOADK(kC0, kC1, kC2, kC3, kqC);   /* K(s+1), regs dead */    \
    unsigned _wpk[8];                                                         \
    _Pragma("unroll")                                                         \
    for (int j = 0; j < 8; ++j) {                                             \
        const float _pa = __builtin_amdgcn_exp2f(_d[2*j]);                    \
        const float _pc = __builtin_amdgcn_exp2f(_d[2*j+1]);                  \
        den[j & 3] += _pa + _pc;                                              \
        _wpk[j] = pack_bf16(_pa, _pc);                                        \
    }                                                                         \
    bf16x8 _pb0, _pb1;                                                        \
    {                                                                         \
        unsigned _a0 = _wpk[0], _b0 = _wpk[2];                                \
        unsigned _a1 = _wpk[1], _b1 = _wpk[3];                                \
        asm volatile("v_permlane32_swap_b32 %0, %1" : "+v"(_a0), "+v"(_b0));  \
        asm volatile("v_permlane32_swap_b32 %0, %1" : "+v"(_a1), "+v"(_b1));  \
        u32x4 _pu = {_a0, _a1, _b0, _b1};                                     \
        _pb0 = __builtin_bit_cast(bf16x8, _pu);                               \
    }                                                                         \
    {                                                                         \
        unsigned _a0 = _wpk[4], _b0 = _wpk[6];                                \
        unsigned _a1 = _wpk[5], _b1 = _wpk[7];                                \
        asm volatile("v_permlane32_swap_b32 %0, %1" : "+v"(_a0), "+v"(_b0));  \
        asm volatile("v_permlane32_swap_b32 %0, %1" : "+v"(_a1), "+v"(_b1));  \
        u32x4 _pu = {_a0, _a1, _b0, _b1};                                     \
        _pb1 = __builtin_bit_cast(bf16x8, _pu);                               \
    }                                                                         \
    /* PV from LDS: linear lane-ordered reads (conflict-free) */              \
    _Pragma("unroll")                                                         \
    for (int j = 0; j < 4; ++j)                                               \
        va[j] = *(const bf16x8*)((vcur) + j * 512 + vloff);                   \
    _Pragma("unroll")                                                         \
    for (int j = 0; j < 4; ++j)                                               \
        vb[j] = *(const bf16x8*)((vcur) + (4 + j) * 512 + vloff);             \
    __builtin_amdgcn_s_setprio(1);                                            \
    _Pragma("unroll")                                                         \
    for (int j = 0; j < 4; ++j)                                               \
        acc[j] = mfma32(va[j], _pb0, acc[j]);                                 \
    __builtin_amdgcn_s_setprio(0);                                            \
    _Pragma("unroll")                                                         \
    for (int j = 0; j < 4; ++j)                                               \
        va[j] = *(const bf16x8*)((vcur) + 4096 + j * 512 + vloff);            \
    __builtin_amdgcn_s_setprio(1);                                            \
    _Pragma("unroll")                                                         \
    for (int j = 0; j < 4; ++j)                                               \
        acc[4 + j] = mfma32(vb[j], _pb0, acc[4 + j]);                         \
    __builtin_amdgcn_s_setprio(0);                                            \
    _Pragma("unroll")                                                         \
    for (int j = 0; j < 4; ++j)                                               \
        vb[j] = *(const bf16x8*)((vcur) + 4096 + (4 + j) * 512 + vloff);      \
    __builtin_amdgcn_s_setprio(1);                                            \
    _Pragma("unroll")                                                         \
    for (int j = 0; j < 4; ++j)                                               \
        acc[j] = mfma32(va[j], _pb1, acc[j]);                                 \
    _Pragma("unroll")                                                         \
    for (int j = 0; j < 4; ++j)                                               \
        acc[4 + j] = mfma32(vb[j], _pb1, acc[4 + j]);                         \
    __builtin_amdgcn_s_setprio(0);                                            \
} while (0)

__global__ __launch_bounds__(256, 2) void flash12_kernel(const __bf16* __restrict__ ktile,
                                                         const float* __restrict__ qk,
                                                         const __bf16* __restrict__ vt,
                                                         const unsigned* __restrict__ ksq2,
                                                         __bf16* __restrict__ partO,
                                                         float* __restrict__ partD) {
    const int tid = threadIdx.x;
    const int w = tid >> 6, lane = tid & 63;
    const int l31 = lane & 31, h = lane >> 5;

    // XCD-chunked decomposition: 32 groups (cs2,s,b) x 18 blocks; a group's
    // 72 waves share one K/V-segment stream -> one XCD's L2.
    const int bid = blockIdx.x;            // 0..575
    const int xcd = bid & 7;
    const int ixc = bid >> 3;              // 0..71
    const int grp = ixc / 18;              // 0..3
    const int blk = ixc % 18;              // 0..17
    const int G   = xcd * 4 + grp;         // 0..31
    const int cs2 = G & 1;
    const int sb  = G >> 1;                // 0..15
    const int s   = sb & 7, b = sb >> 3;
    const int nt  = blk * 4 + w;           // 0..71

    const int n0 = nt * 32;
    const int cw = cs2 * 256;
    const int m_base = s * MSEG;

    // lane-invariant offsets (elements), computed ONCE
    const int koff  = (h * 32 + l31) * 8;
    const int vloff = lane * 8;                        // linear LDS frag read
    const int cwoff = cw * 16;                         // channel-window in vt chunk
    const int soff  = (lane & 31) * 16 + (lane >> 5) * 8;  // pre-swizzled global src

    // shared V strip buffers: fragment-ordered copy, 2 x 16KB
    __shared__ __align__(16) __bf16 Vlds[2][8192];

    // Q' B-frags: col = n0+l31, k = 16ks+8h+i, scaled by C2Q
    const float* qkb = qk + (size_t)b * CK_ * N_;
    bf16x8 qf[4];
#pragma unroll
    for (int ks = 0; ks < 4; ++ks)
#pragma unroll
      for (int i = 0; i < 8; ++i)
        qf[ks][i] = (__bf16)(qkb[(size_t)(16*ks + 8*h + i) * N_ + (n0 + l31)] * C2Q);

    // constant B-frag: -1.0bf16 at k slots {0,1}
    const u32x4 bneg_u = {0xBF80BF80u, 0u, 0u, 0u};
    const bf16x8 bneg = __builtin_bit_cast(bf16x8, bneg_u);

    // persistent zero accumulator (C operand of the first QK MFMA)
    f32x16 fzero;
#pragma unroll
    for (int r = 0; r < 16; ++r) fzero[r] = 0.f;

    // wave-uniform stream pointers, advanced by constant strides (SALU)
    const __bf16*   kp  = ktile + (size_t)b * M_ * 64 + (size_t)m_base * 64;
    const unsigned* kqp = ksq2  + (size_t)b * M_ + m_base;
    const __bf16*   vps = vt    + (size_t)b * M_ * CV_ + (size_t)m_base * CV_;

    f32x16 acc[8];
#pragma unroll
    for (int ct = 0; ct < 8; ++ct)
#pragma unroll
      for (int r = 0; r < 16; ++r) acc[ct][r] = 0.f;
    float den[4] = {0.f, 0.f, 0.f, 0.f};

    bf16x8 kC0, kC1, kC2, kC3;
    unsigned kqC;
    bf16x8 va[4], vb[4];

    // prologue: K(0) regs + V(0) staged into buf0
    LOADK(kC0, kC1, kC2, kC3, kqC);
    STAGEV(&Vlds[0][0]);

    for (int mss = 0; mss < 35; ++mss) {              // strips 0..69
        BODY(&Vlds[0][0], &Vlds[1][0], 1, 1);
        BODY(&Vlds[1][0], &Vlds[0][0], 1, 1);
    }
    BODY(&Vlds[0][0], &Vlds[1][0], 1, 1);             // strip 70 (stages 71)
    BODY(&Vlds[1][0], &Vlds[0][0], 0, 0);             // strip 71

    // denominator: lane holds sum over its 16 m-rows; add other half
    float dsum = (den[0] + den[1]) + (den[2] + den[3]);
    dsum += __shfl_xor(dsum, 32);
    if (cs2 == 0 && lane < 32)
        partD[(size_t)(s * B_ + b) * N_ + n0 + l31] = dsum;

    // unnormalized partial O in bf16: c = cw + 32ct + (r&3)+8*(r>>2)+4h
    __bf16* po = partO + (((size_t)(s * B_ + b) * CV_ + cw) * N_) + n0 + l31;
#pragma unroll
    for (int ct = 0; ct < 8; ++ct)
#pragma unroll
      for (int r = 0; r < 16; ++r) {
        const int crow = 32*ct + (r & 3) + 8*(r >> 2) + 4*h;
        po[(size_t)crow * N_] = (__bf16)acc[ct][r];
      }
}

// ---------------------------------------------------------------------------
// reduce: mem[b][c][n] = sum_s partO / sum_s partD  -> d_out channels 0..511
// ---------------------------------------------------------------------------
__global__ __launch_bounds__(256) void reduce_kernel(const __bf16* __restrict__ partO,
                                                     const float* __restrict__ partD,
                                                     float* __restrict__ out) {
    const int idx = blockIdx.x * 256 + threadIdx.x;   // B*CV*(N/8) threads
    const int n8 = idx % (N_ / 8);
    const int c  = (idx / (N_ / 8)) % CV_;
    const int b  = idx / ((N_ / 8) * CV_);
    float o[8] = {0,0,0,0,0,0,0,0};
    float dd[8] = {0,0,0,0,0,0,0,0};
#pragma unroll
    for (int s = 0; s < SSPLIT; ++s) {
        const bf16x8 ov = *(const bf16x8*)(partO + (((size_t)(s*B_+b)*CV_ + c) * N_) + n8*8);
        const float4 d0 = *(const float4*)(partD + (size_t)(s*B_+b)*N_ + n8*8);
        const float4 d1 = *(const float4*)(partD + (size_t)(s*B_+b)*N_ + n8*8 + 4);
#pragma unroll
        for (int j = 0; j < 8; ++j) o[j] += (float)ov[j];
        dd[0]+=d0.x; dd[1]+=d0.y; dd[2]+=d0.z; dd[3]+=d0.w;
        dd[4]+=d1.x; dd[5]+=d1.y; dd[6]+=d1.z; dd[7]+=d1.w;
    }
    float* op = out + ((size_t)b * (2*CV_) + c) * N_ + n8*8;
#pragma unroll
    for (int j = 0; j < 8; ++j) op[j] = o[j] / dd[j];
}

// ---------------------------------------------------------------------------
// conv_r: R_j[cc][b][p] = sum_{c in chunk cc} in[c][p] * w[c][j]
// ---------------------------------------------------------------------------
__global__ __launch_bounds__(256) void conv_r_kernel(const float* __restrict__ outf,
                                                     const float* __restrict__ qv,
                                                     const float* __restrict__ mask,
                                                     const float* __restrict__ cw,
                                                     float* __restrict__ Rp) {
    const int p  = blockIdx.x * 256 + threadIdx.x;   // 0..N-1
    const int cc = blockIdx.y;                        // 0..8
    const int b  = blockIdx.z;
    float r[9] = {0,0,0,0,0,0,0,0,0};
    if (cc < 8) {
        const float* src = (cc < 4) ? outf + ((size_t)b * (2*CV_) + cc * 128) * N_
                                    : qv   + ((size_t)b * CV_ + (cc - 4) * 128) * N_;
        const float* wb = cw + (size_t)cc * 128 * 9;
        for (int c = 0; c < 128; ++c) {
            const float v = src[(size_t)c * N_ + p];
#pragma unroll
            for (int j = 0; j < 9; ++j) r[j] += v * wb[c * 9 + j];
        }
    } else {
        const float v = mask[(size_t)b * N_ + p];
#pragma unroll
        for (int j = 0; j < 9; ++j) r[j] = v * cw[1024 * 9 + j];
    }
#pragma unroll
    for (int j = 0; j < 9; ++j)
        Rp[(((size_t)cc * 9 + j) * B_ + b) * N_ + p] = r[j];
}

// ---------------------------------------------------------------------------
// gate: gate[b][p] = sigmoid( sum_j sum_cc Rp[cc][j][b][neighbor_j(p)] + bias )
// ---------------------------------------------------------------------------
__global__ __launch_bounds__(256) void gate_kernel(const float* __restrict__ Rp,
                                                   const float* __restrict__ cbias,
                                                   float* __restrict__ gate_ws) {
    const int p = blockIdx.x * 256 + threadIdx.x;    // 0..N-1
    const int b = blockIdx.y;
    const int y = p / W_, x = p % W_;
    float sum = cbias[0];
#pragma unroll
    for (int dy = -1; dy <= 1; ++dy) {
        const int yy = y + dy;
        if (yy < 0 || yy >= H_) continue;
#pragma unroll
        for (int dx = -1; dx <= 1; ++dx) {
            const int xx = x + dx;
            if (xx < 0 || xx >= W_) continue;
            const int j = (dy + 1) * 3 + (dx + 1);
            const int q = yy * W_ + xx;
#pragma unroll
            for (int cc = 0; cc < 9; ++cc)
                sum += Rp[(((size_t)cc * 9 + j) * B_ + b) * N_ + q];
        }
    }
    gate_ws[(size_t)b * N_ + p] = 1.f / (1.f + __builtin_amdgcn_exp2f(-sum * 1.44269504f));
}

// ---------------------------------------------------------------------------
// finalize: out[b][ch][n] = (ch<512 ? mem : qv) * gate[b][n]
// ---------------------------------------------------------------------------
__global__ __launch_bounds__(256) void finalize_kernel(const float* __restrict__ qv,
                                                       const float* __restrict__ gate_ws,
                                                       float* __restrict__ out) {
    const int idx = blockIdx.x * 256 + threadIdx.x;
    const int n4 = N_ / 4;
    const int pos4 = idx % n4;
    const int row  = idx / n4;
    const int b = row >> 10, ch = row & 1023;
    const float4 gv = *(const float4*)(gate_ws + (size_t)b * N_ + pos4 * 4);
    float* op = out + (size_t)row * N_ + pos4 * 4;
    float4 v;
    if (ch < CV_) v = *(const float4*)op;
    else          v = *(const float4*)(qv + ((size_t)b * CV_ + (ch - CV_)) * N_ + pos4 * 4);
    v.x *= gv.x; v.y *= gv.y; v.z *= gv.z; v.w *= gv.w;
    *(float4*)op = v;
}

// ===========================================================================
extern "C" void kernel_launch(void* const* d_in, const int* in_sizes, int n_in,
                              void* d_out, int out_size, void* d_ws, size_t ws_size,
                              hipStream_t stream) {
    (void)in_sizes; (void)n_in; (void)out_size; (void)ws_size;
    const float* mk    = (const float*)d_in[0];
    const float* qk    = (const float*)d_in[1];
    const float* mv    = (const float*)d_in[2];
    const float* qv    = (const float*)d_in[3];
    const float* mask  = (const float*)d_in[4];
    const float* cw    = (const float*)d_in[5];
    const float* cbias = (const float*)d_in[6];
    float* outf = (float*)d_out;

    // workspace layout (bytes) — total 80,529,408, byte-identical to rounds 3-13
    const size_t kbf_b   = (size_t)B_ * M_ * 64 * 2;             //  4,718,592 (ktile; reused as Rp)
    const size_t vbf_b   = (size_t)B_ * CV_ * M_ * 2;            // 37,748,736 (vt)
    const size_t ksq_b   = (size_t)B_ * M_ * 4;                  //    147,456 (packed u32 hi/lo)
    const size_t partO_b = (size_t)SSPLIT * B_ * CV_ * N_ * 2;   // 37,748,736 (bf16)
    const size_t partD_b = (size_t)SSPLIT * B_ * N_ * 4;         //    147,456

    char* pw = (char*)d_ws;
    __bf16* ktile = (__bf16*)pw;
    float*  Rp    = (float*)pw;            // overlays ktile (dead after flash12)
    pw += kbf_b;
    __bf16* vt    = (__bf16*)pw;           pw += vbf_b;
    unsigned* ksq2 = (unsigned*)pw;        pw += ksq_b;
    __bf16* partO = (__bf16*)pw;           pw += partO_b;
    float*  partD = (float*)pw;            pw += partD_b;
    float*  gate_ws = (float*)pw;

    prep_k<<<dim3(B_ * M_ / 256), 256, 0, stream>>>(mk, ktile, ksq2);
    prep_v<<<dim3((size_t)B_ * (M_ / 16) * CV_ / 256, 1, 1), 256, 0, stream>>>(mv, vt);
    flash12_kernel<<<dim3(576), 256, 0, stream>>>(ktile, qk, vt, ksq2, partO, partD);
    reduce_kernel<<<dim3(B_ * CV_ * (N_ / 8) / 256), 256, 0, stream>>>(partO, partD, outf);
    conv_r_kernel<<<dim3(N_ / 256, 9, B_), 256, 0, stream>>>(outf, qv, mask, cw, Rp);
    gate_kernel<<<dim3(N_ / 256, B_), 256, 0, stream>>>(Rp, cbias, gate_ws);
    finalize_kernel<<<dim3((B_ * 2 * CV_ * N_ / 4) / 256), 256, 0, stream>>>(qv, gate_ws, outf);
}